// Round 11
// baseline (194.865 us; speedup 1.0000x reference)
//
#include <hip/hip_runtime.h>
#include <hip/hip_fp16.h>
#include <math.h>

#define NODES 100000
#define NEDGE 1600000
#define ETOT  (NEDGE + NODES)
#define FIN   128
#define C1    64
#define NEG   0.2f
#define BNEPS 1e-5f
#define BNBLK 256

#define BK     128                         // nodes per bucket
#define NBUCK  ((NODES + BK - 1) / BK)     // 782
#define PCAP   2816                        // per-bucket edge cap (mean 2048, +17 sigma)
#define PTILE  4096                        // edges per k_part block

typedef __attribute__((ext_vector_type(8))) short bf16x8;
typedef __attribute__((ext_vector_type(4))) float f32x4;

static __device__ __forceinline__ short f2bf(float f) {
    unsigned u = __builtin_bit_cast(unsigned, f);
    unsigned r = (u + 0x7FFFu + ((u >> 16) & 1u)) >> 16;
    return (short)r;
}

// ---------------- bucketed CSR build ----------------

__global__ __launch_bounds__(256) void k_zeroN(int* p, int n) {
    int i = blockIdx.x * 256 + threadIdx.x;
    if (i < n) p[i] = 0;
}

// P1: partition edges into buckets by dst>>7; pack src | (dst&127)<<17
__global__ __launch_bounds__(256) void k_part(const int* __restrict__ ei, int* bcur,
                                              unsigned* __restrict__ tmp) {
    __shared__ int hist[NBUCK], hbase[NBUCK], run[NBUCK];
    int t = threadIdx.x;
    for (int i = t; i < NBUCK; i += 256) { hist[i] = 0; run[i] = 0; }
    __syncthreads();
    const int* srcs = ei;
    const int* dsts = ei + NEDGE;
    int e_base = blockIdx.x * PTILE;
    unsigned pack[16];
    int bkt[16];
    #pragma unroll
    for (int i = 0; i < 16; i++) {
        int e = e_base + i * 256 + t;
        bool valid = e < NEDGE;
        int s = valid ? srcs[e] : 0;
        int d = valid ? dsts[e] : 0;
        if ((unsigned)d >= NODES || (unsigned)s >= NODES) valid = false;
        bkt[i] = valid ? (d >> 7) : -1;
        pack[i] = (unsigned)s | ((unsigned)(d & (BK - 1)) << 17);
        if (valid) atomicAdd(&hist[bkt[i]], 1);
    }
    __syncthreads();
    for (int i = t; i < NBUCK; i += 256)
        hbase[i] = hist[i] ? atomicAdd(&bcur[i], hist[i]) : 0;
    __syncthreads();
    #pragma unroll
    for (int i = 0; i < 16; i++) {
        if (bkt[i] >= 0) {
            int slot = atomicAdd(&run[bkt[i]], 1) + hbase[bkt[i]];
            if (slot < PCAP) tmp[(size_t)bkt[i] * PCAP + slot] = pack[i];
        }
    }
}

// exclusive scan of NBUCK bucket totals (single block, 4 items/thread)
__global__ __launch_bounds__(256) void k_bscan(const int* __restrict__ bcur, int* __restrict__ bbase) {
    __shared__ int lds[256];
    int t = threadIdx.x;
    int base = t * 4;
    int v0 = (base + 0) < NBUCK ? bcur[base + 0] : 0;
    int v1 = (base + 1) < NBUCK ? bcur[base + 1] : 0;
    int v2 = (base + 2) < NBUCK ? bcur[base + 2] : 0;
    int v3 = (base + 3) < NBUCK ? bcur[base + 3] : 0;
    int tot = v0 + v1 + v2 + v3;
    lds[t] = tot;
    __syncthreads();
    for (int o = 1; o < 256; o <<= 1) {
        int add = (t >= o) ? lds[t - o] : 0;
        __syncthreads();
        lds[t] += add;
        __syncthreads();
    }
    int excl = lds[t] - tot;
    if (base + 0 < NBUCK) bbase[base + 0] = excl;
    if (base + 1 < NBUCK) bbase[base + 1] = excl + v0;
    if (base + 2 < NBUCK) bbase[base + 2] = excl + v0 + v1;
    if (base + 3 < NBUCK) bbase[base + 3] = excl + v0 + v1 + v2;
}

// P2: per bucket: counts -> local scan (offs) -> LDS scatter -> coalesced csr+dsl write
__global__ __launch_bounds__(256) void k_build(const unsigned* __restrict__ tmp, const int* __restrict__ bcur,
                                               const int* __restrict__ bbase, int* __restrict__ offs,
                                               int* __restrict__ csr, int* __restrict__ dsl) {
    __shared__ int cnt[BK];
    __shared__ int ps_[BK];
    __shared__ int stage[PCAP + BK];
    int t = threadIdx.x;
    int b = blockIdx.x;
    int ecnt = bcur[b]; if (ecnt > PCAP) ecnt = PCAP;
    int csrbase = bbase[b] + BK * b;   // earlier buckets all have BK self-loops
    const unsigned* ebuf = tmp + (size_t)b * PCAP;

    if (t < BK) cnt[t] = 0;
    __syncthreads();
    for (int e = t; e < ecnt; e += 256) {
        int dl = (ebuf[e] >> 17) & (BK - 1);
        atomicAdd(&cnt[dl], 1);
    }
    __syncthreads();
    int gn = b * BK + t;
    int own = 0;
    if (t < BK) {
        own = cnt[t] + ((gn < NODES) ? 1 : 0);   // +1 self-loop
        ps_[t] = own;
    }
    __syncthreads();
    for (int o = 1; o < BK; o <<= 1) {
        int add = (t < BK && t >= o) ? ps_[t - o] : 0;
        __syncthreads();
        if (t < BK) ps_[t] += add;
        __syncthreads();
    }
    int total = ps_[BK - 1];
    if (t < BK && gn < NODES) {
        int excl = ps_[t] - own;
        stage[excl] = gn | (t << 17);     // self-loop, packed (src=gn, dl=t)
        cnt[t] = excl + 1;
        offs[gn] = csrbase + excl;
    }
    if (b == NBUCK - 1 && t == 0) offs[NODES] = ETOT;
    __syncthreads();
    for (int e = t; e < ecnt; e += 256) {
        unsigned p = ebuf[e];
        int dl = (p >> 17) & (BK - 1);
        int slot = atomicAdd(&cnt[dl], 1);
        stage[slot] = (int)p;
    }
    __syncthreads();
    for (int j = t; j < total; j += 256) {
        int v = stage[j];
        csr[csrbase + j] = v & 0x1FFFF;
        dsl[csrbase + j] = b * BK + (int)(((unsigned)v) >> 17);
    }
}

// ---------------- prep: wad vectors + W1s bf16 B-fragments ----------------

__global__ __launch_bounds__(256) void k_prep(const float* __restrict__ W1s,
                                              const float* __restrict__ W1d, const float* __restrict__ a1d,
                                              const float* __restrict__ W2d, const float* __restrict__ a2d,
                                              float* wad1, float* wad2, unsigned short* __restrict__ wfrag) {
    int t = threadIdx.x;
    int b = blockIdx.x;
    if (b == 32) {
        if (t < FIN) {
            float acc = 0.f;
            for (int c = 0; c < C1; c++) acc = fmaf(W1d[t * C1 + c], a1d[c], acc);
            wad1[t] = acc;
        }
        if (t < C1) {
            wad2[t] = fmaf(W2d[t * 2], a2d[0], W2d[t * 2 + 1] * a2d[1]);
        }
    } else {
        int idx = b * 256 + t;          // 0..8191
        int j  = idx & 7;
        int ln = (idx >> 3) & 63;
        int it = (idx >> 9) & 3;
        int ct = idx >> 11;
        int k  = it * 32 + (ln >> 4) * 8 + j;
        int ch = ct * 16 + (ln & 15);
        wfrag[idx] = (unsigned short)f2bf(W1s[k * C1 + ch]);
    }
}

// ---------------- GEMM1 via MFMA (unchanged from round 10) ----------------

__global__ __launch_bounds__(256) void k_gemm1(const float* __restrict__ x,
                                               const unsigned short* __restrict__ wfrag,
                                               const float* __restrict__ wad, const float* __restrict__ a_src,
                                               __half* __restrict__ hsh, float* __restrict__ as_out,
                                               float* __restrict__ ad_out) {
    int t = threadIdx.x;
    int lane = t & 63;
    int wv = t >> 6;
    int n0 = blockIdx.x * 64 + wv * 16;
    int li = lane & 15, g = lane >> 4;

    int row = n0 + li;
    bool rv = row < NODES;
    const float* xr = x + (size_t)row * FIN + g * 8;

    f32x4 acc0 = {0.f,0.f,0.f,0.f}, acc1 = {0.f,0.f,0.f,0.f};
    f32x4 acc2 = {0.f,0.f,0.f,0.f}, acc3 = {0.f,0.f,0.f,0.f};
    bf16x8 af[4];
    float adp = 0.f;

    #pragma unroll
    for (int it = 0; it < 4; it++) {
        float xv[8];
        if (rv) {
            float4 lo = *reinterpret_cast<const float4*>(xr + it * 32);
            float4 hi = *reinterpret_cast<const float4*>(xr + it * 32 + 4);
            xv[0]=lo.x; xv[1]=lo.y; xv[2]=lo.z; xv[3]=lo.w;
            xv[4]=hi.x; xv[5]=hi.y; xv[6]=hi.z; xv[7]=hi.w;
        } else {
            #pragma unroll
            for (int j = 0; j < 8; j++) xv[j] = 0.f;
        }
        const float* wr = wad + g * 8 + it * 32;
        float4 wlo = *reinterpret_cast<const float4*>(wr);
        float4 whi = *reinterpret_cast<const float4*>(wr + 4);
        adp = fmaf(xv[0], wlo.x, adp); adp = fmaf(xv[1], wlo.y, adp);
        adp = fmaf(xv[2], wlo.z, adp); adp = fmaf(xv[3], wlo.w, adp);
        adp = fmaf(xv[4], whi.x, adp); adp = fmaf(xv[5], whi.y, adp);
        adp = fmaf(xv[6], whi.z, adp); adp = fmaf(xv[7], whi.w, adp);
        bf16x8 a;
        #pragma unroll
        for (int j = 0; j < 8; j++) a[j] = f2bf(xv[j]);
        af[it] = a;
    }

    const bf16x8* wfv = reinterpret_cast<const bf16x8*>(wfrag);
    #pragma unroll
    for (int it = 0; it < 4; it++) {
        acc0 = __builtin_amdgcn_mfma_f32_16x16x32_bf16(af[it], wfv[(0*4+it)*64 + lane], acc0, 0, 0, 0);
        acc1 = __builtin_amdgcn_mfma_f32_16x16x32_bf16(af[it], wfv[(1*4+it)*64 + lane], acc1, 0, 0, 0);
        acc2 = __builtin_amdgcn_mfma_f32_16x16x32_bf16(af[it], wfv[(2*4+it)*64 + lane], acc2, 0, 0, 0);
        acc3 = __builtin_amdgcn_mfma_f32_16x16x32_bf16(af[it], wfv[(3*4+it)*64 + lane], acc3, 0, 0, 0);
    }

    adp += __shfl_xor(adp, 16);
    adp += __shfl_xor(adp, 32);
    if (lane < 16 && rv) ad_out[row] = adp;

    float a0 = a_src[0 * 16 + li], a1 = a_src[1 * 16 + li];
    float a2 = a_src[2 * 16 + li], a3 = a_src[3 * 16 + li];
    float asp0 = acc0[0]*a0 + acc1[0]*a1 + acc2[0]*a2 + acc3[0]*a3;
    float asp1 = acc0[1]*a0 + acc1[1]*a1 + acc2[1]*a2 + acc3[1]*a3;
    float asp2 = acc0[2]*a0 + acc1[2]*a1 + acc2[2]*a2 + acc3[2]*a3;
    float asp3 = acc0[3]*a0 + acc1[3]*a1 + acc2[3]*a2 + acc3[3]*a3;
    #pragma unroll
    for (int o = 1; o <= 8; o <<= 1) {
        asp0 += __shfl_xor(asp0, o);
        asp1 += __shfl_xor(asp1, o);
        asp2 += __shfl_xor(asp2, o);
        asp3 += __shfl_xor(asp3, o);
    }
    if ((lane & 12) == 0) {
        int r = lane & 3;
        int n = n0 + 4 * g + r;
        if (n < NODES) {
            float av = (r == 0) ? asp0 : (r == 1) ? asp1 : (r == 2) ? asp2 : asp3;
            as_out[n] = av;
        }
    }

    #pragma unroll
    for (int r = 0; r < 4; r++) {
        int n = n0 + 4 * g + r;
        if (n < NODES) {
            __half* hb = hsh + (size_t)n * C1 + li;
            hb[ 0] = __float2half(acc0[r]);
            hb[16] = __float2half(acc1[r]);
            hb[32] = __float2half(acc2[r]);
            hb[48] = __float2half(acc3[r]);
        }
    }
}

// ---------------- edge pass 1: p = exp(lrelu(as1[src]+ad1[dst])), packed (s,p) ----------------
// as1/ad1 are L2-resident (400KB each); csr/dsl coalesced. pe padded +8 with zeros.

__global__ __launch_bounds__(256) void k_edges1(const int* __restrict__ csr, const int* __restrict__ dsl,
                                                const float* __restrict__ as1, const float* __restrict__ ad1,
                                                uint2* __restrict__ pe) {
    int e = blockIdx.x * 256 + threadIdx.x;
    if (e >= ETOT + 8) return;
    if (e < ETOT) {
        int s = csr[e];
        float v = as1[s] + ad1[dsl[e]];
        v = v > 0.f ? v : NEG * v;
        float p = __expf(fminf(v, 60.f));
        pe[e] = make_uint2((unsigned)s, __float_as_uint(p));
    } else {
        pe[e] = make_uint2(0u, 0u);
    }
}

// ---------------- aggregation layer 1: pure gather (no softmax work in-loop) ----------------
// wave per node; 4 groups x 16 lanes; group reads (s,p) via one broadcast 8B load,
// lane reads half4 (8B) -> one vmem instruction covers 4 rows. 2x unroll. Invalid
// slots clamp to row 0 (L1-hot) with p=0.

__global__ __launch_bounds__(256) void k_agg1(const int* __restrict__ offs, const uint2* __restrict__ pe,
                                              const __half* __restrict__ hsh, const float* __restrict__ b1,
                                              float* __restrict__ h1) {
    int w = threadIdx.x >> 6, lane = threadIdx.x & 63;
    int node = blockIdx.x * 4 + w;
    if (node >= NODES) return;
    int e0 = offs[node], e1 = offs[node + 1];
    int g = lane >> 4, l = lane & 15;
    float acc0 = 0.f, acc1 = 0.f, acc2 = 0.f, acc3 = 0.f, ssum = 0.f;
    for (int base = e0; base < e1; base += 8) {
        int ea = base + g, eb = ea + 4;
        uint2 spa = pe[ea];
        uint2 spb = pe[eb];
        bool va = ea < e1, vb = eb < e1;
        int   sa = va ? (int)spa.x : 0;
        int   sb = vb ? (int)spb.x : 0;
        float pa = va ? __uint_as_float(spa.y) : 0.f;
        float pb = vb ? __uint_as_float(spb.y) : 0.f;
        uint2 ra = *reinterpret_cast<const uint2*>(hsh + (size_t)sa * C1 + l * 4);
        uint2 rb = *reinterpret_cast<const uint2*>(hsh + (size_t)sb * C1 + l * 4);
        ssum += pa + pb;
        float2 a01 = __half22float2(*reinterpret_cast<const __half2*>(&ra.x));
        float2 a23 = __half22float2(*reinterpret_cast<const __half2*>(&ra.y));
        float2 b01 = __half22float2(*reinterpret_cast<const __half2*>(&rb.x));
        float2 b23 = __half22float2(*reinterpret_cast<const __half2*>(&rb.y));
        acc0 = fmaf(pa, a01.x, acc0); acc1 = fmaf(pa, a01.y, acc1);
        acc2 = fmaf(pa, a23.x, acc2); acc3 = fmaf(pa, a23.y, acc3);
        acc0 = fmaf(pb, b01.x, acc0); acc1 = fmaf(pb, b01.y, acc1);
        acc2 = fmaf(pb, b23.x, acc2); acc3 = fmaf(pb, b23.y, acc3);
    }
    ssum += __shfl_xor(ssum, 16); ssum += __shfl_xor(ssum, 32);
    acc0 += __shfl_xor(acc0, 16); acc0 += __shfl_xor(acc0, 32);
    acc1 += __shfl_xor(acc1, 16); acc1 += __shfl_xor(acc1, 32);
    acc2 += __shfl_xor(acc2, 16); acc2 += __shfl_xor(acc2, 32);
    acc3 += __shfl_xor(acc3, 16); acc3 += __shfl_xor(acc3, 32);
    if (g == 0) {
        float inv = 1.0f / (ssum + 1e-16f);
        float4 bv = reinterpret_cast<const float4*>(b1)[l];
        float4 r = make_float4(fmaf(acc0, inv, bv.x), fmaf(acc1, inv, bv.y),
                               fmaf(acc2, inv, bv.z), fmaf(acc3, inv, bv.w));
        reinterpret_cast<float4*>(h1 + (size_t)node * C1)[l] = r;
    }
}

// ---------------- BN stats: deterministic per-block partials ----------------

__global__ __launch_bounds__(256) void k_bnstats(const float* __restrict__ h1, float* __restrict__ bnpart) {
    __shared__ float ls[256], lq[256];
    int t = threadIdx.x;
    int c = t & 63, g = t >> 6;
    float s = 0.f, q = 0.f;
    for (int n = blockIdx.x * 4 + g; n < NODES; n += BNBLK * 4) {
        float v = h1[(size_t)n * C1 + c];
        s += v;
        q = fmaf(v, v, q);
    }
    ls[t] = s; lq[t] = q;
    __syncthreads();
    if (t < 64) {
        bnpart[(size_t)blockIdx.x * 128 + t]      = ls[t] + ls[t + 64] + ls[t + 128] + ls[t + 192];
        bnpart[(size_t)blockIdx.x * 128 + 64 + t] = lq[t] + lq[t + 64] + lq[t + 128] + lq[t + 192];
    }
}

__global__ __launch_bounds__(64) void k_bnfinal(const float* __restrict__ bnpart,
                                                const float* __restrict__ gamma, const float* __restrict__ beta,
                                                float* bnscale, float* bnshift) {
    int c = threadIdx.x;
    if (c < C1) {
        float s = 0.f, q = 0.f;
        for (int b = 0; b < BNBLK; b++) {
            s += bnpart[(size_t)b * 128 + c];
            q += bnpart[(size_t)b * 128 + 64 + c];
        }
        float mu = s * (1.0f / NODES);
        float var = q * (1.0f / NODES) - mu * mu;
        if (var < 0.f) var = 0.f;
        float rinv = 1.0f / sqrtf(var + BNEPS);
        float sc = gamma[c] * rinv;
        bnscale[c] = sc;
        bnshift[c] = beta[c] - mu * sc;
    }
}

// ---------------- BN apply + ReLU + GEMM2 (+alpha dots) ----------------

__global__ __launch_bounds__(256) void k_bngemm2(const float* __restrict__ h1, const float* __restrict__ bnscale,
                                                 const float* __restrict__ bnshift, const float* __restrict__ W2s,
                                                 const float* __restrict__ wad2, const float* __restrict__ a2s,
                                                 float* __restrict__ hs2, float* __restrict__ as2,
                                                 float* __restrict__ ad2) {
    int n = blockIdx.x * 256 + threadIdx.x;
    if (n >= NODES) return;
    const float4* hr = reinterpret_cast<const float4*>(h1 + (size_t)n * C1);
    float h0 = 0.f, h1v = 0.f, adv = 0.f;
    #pragma unroll
    for (int c4 = 0; c4 < 16; c4++) {
        float4 v = hr[c4];
        float vv[4] = {v.x, v.y, v.z, v.w};
        #pragma unroll
        for (int j = 0; j < 4; j++) {
            int c = c4 * 4 + j;
            float y = fmaf(vv[j], bnscale[c], bnshift[c]);
            y = fmaxf(y, 0.f);
            h0 = fmaf(y, W2s[c * 2 + 0], h0);
            h1v = fmaf(y, W2s[c * 2 + 1], h1v);
            adv = fmaf(y, wad2[c], adv);
        }
    }
    hs2[n * 2 + 0] = h0;
    hs2[n * 2 + 1] = h1v;
    as2[n] = fmaf(h0, a2s[0], h1v * a2s[1]);
    ad2[n] = adv;
}

// ---------------- aggregation layer 2: wave per node, fully lane-parallel ----------------

__global__ __launch_bounds__(256) void k_agg2(const int* __restrict__ offs, const int* __restrict__ csr,
                                              const float* __restrict__ as2, const float* __restrict__ ad2,
                                              const float* __restrict__ hs2, const float* __restrict__ b2,
                                              float* __restrict__ out) {
    int w = threadIdx.x >> 6, lane = threadIdx.x & 63;
    int node = blockIdx.x * 4 + w;
    if (node >= NODES) return;
    int e0 = offs[node], e1 = offs[node + 1];
    float adn = ad2[node];
    float ssum = 0.f, A0 = 0.f, A1 = 0.f;
    const float2* h2 = reinterpret_cast<const float2*>(hs2);
    for (int base = e0; base < e1; base += 64) {
        int e = base + lane;
        bool valid = e < e1;
        int s = valid ? csr[e] : 0;
        float v = valid ? (as2[s] + adn) : -INFINITY;
        v = v > 0.f ? v : NEG * v;
        float p = __expf(fminf(v, 60.f));
        ssum += p;
        float2 hv = valid ? h2[s] : make_float2(0.f, 0.f);
        A0 = fmaf(p, hv.x, A0);
        A1 = fmaf(p, hv.y, A1);
    }
    #pragma unroll
    for (int o = 32; o; o >>= 1) {
        ssum += __shfl_xor(ssum, o);
        A0   += __shfl_xor(A0, o);
        A1   += __shfl_xor(A1, o);
    }
    if (lane == 0) {
        float inv = 1.0f / (ssum + 1e-16f);
        float2 r = make_float2(fmaf(A0, inv, b2[0]), fmaf(A1, inv, b2[1]));
        reinterpret_cast<float2*>(out)[node] = r;
    }
}

// ---------------- host ----------------

static inline size_t align256(size_t x) { return (x + 255) & ~size_t(255); }

extern "C" void kernel_launch(void* const* d_in, const int* in_sizes, int n_in,
                              void* d_out, int out_size, void* d_ws, size_t ws_size,
                              hipStream_t stream) {
    const float* x     = (const float*)d_in[0];
    const int*   ei    = (const int*)d_in[1];
    const float* W1s   = (const float*)d_in[2];
    const float* W1d   = (const float*)d_in[3];
    const float* a1s   = (const float*)d_in[4];
    const float* a1d   = (const float*)d_in[5];
    const float* b1    = (const float*)d_in[6];
    const float* gamma = (const float*)d_in[7];
    const float* beta  = (const float*)d_in[8];
    const float* W2s   = (const float*)d_in[9];
    const float* W2d   = (const float*)d_in[10];
    const float* a2s   = (const float*)d_in[11];
    const float* a2d   = (const float*)d_in[12];
    const float* b2    = (const float*)d_in[13];
    float* out = (float*)d_out;

    char* w = (char*)d_ws;
    size_t off = 0;
    auto alloc = [&](size_t bytes) -> void* {
        void* p = w + off;
        off = align256(off + bytes);
        return p;
    };
    int* offs     = (int*)alloc((size_t)(NODES + 1) * 4);
    int* bcur     = (int*)alloc((size_t)NBUCK * 4);
    int* bbase    = (int*)alloc((size_t)NBUCK * 4);
    int* csr      = (int*)alloc((size_t)ETOT * 4);
    int* dsl      = (int*)alloc((size_t)ETOT * 4);
    uint2* pe     = (uint2*)alloc((size_t)(ETOT + 8) * 8);
    __half* hs1h  = (__half*)alloc((size_t)NODES * C1 * 2);   // fp16 gather payload
    float* as1    = (float*)alloc((size_t)NODES * 4);
    float* ad1    = (float*)alloc((size_t)NODES * 4);
    float* h1     = (float*)alloc((size_t)NODES * C1 * 4);   // aliases csr_tmp (below)
    float* hs2    = (float*)alloc((size_t)NODES * 2 * 4);
    float* as2    = (float*)alloc((size_t)NODES * 4);
    float* ad2    = (float*)alloc((size_t)NODES * 4);
    float* wad1   = (float*)alloc(FIN * 4);
    float* wad2   = (float*)alloc(C1 * 4);
    unsigned short* wfrag = (unsigned short*)alloc(8192 * 2); // W1s bf16 B-fragments
    float* bnpart = (float*)alloc((size_t)BNBLK * 128 * 4);
    float* bnsc   = (float*)alloc(64 * 4);
    float* bnsh   = (float*)alloc(64 * 4);
    if (off > ws_size) return;

    // csr_tmp (NBUCK*PCAP ints = 8.8MB) aliases h1 (25.6MB): k_build fully consumes
    // csr_tmp before k_agg1 produces h1 (in-order stream => safe).
    unsigned* csr_tmp = (unsigned*)h1;

    k_zeroN<<<(NBUCK + 255) / 256, 256, 0, stream>>>(bcur, NBUCK);
    k_part<<<(NEDGE + PTILE - 1) / PTILE, 256, 0, stream>>>(ei, bcur, csr_tmp);
    k_bscan<<<1, 256, 0, stream>>>(bcur, bbase);
    k_build<<<NBUCK, 256, 0, stream>>>(csr_tmp, bcur, bbase, offs, csr, dsl);
    k_prep<<<33, 256, 0, stream>>>(W1s, W1d, a1d, W2d, a2d, wad1, wad2, wfrag);
    k_gemm1<<<(NODES + 63) / 64, 256, 0, stream>>>(x, wfrag, wad1, a1s, hs1h, as1, ad1);
    k_edges1<<<(ETOT + 8 + 255) / 256, 256, 0, stream>>>(csr, dsl, as1, ad1, pe);
    k_agg1<<<(NODES + 3) / 4, 256, 0, stream>>>(offs, pe, hs1h, b1, h1);
    k_bnstats<<<BNBLK, 256, 0, stream>>>(h1, bnpart);
    k_bnfinal<<<1, 64, 0, stream>>>(bnpart, gamma, beta, bnsc, bnsh);
    k_bngemm2<<<(NODES + 255) / 256, 256, 0, stream>>>(h1, bnsc, bnsh, W2s, wad2, a2s, hs2, as2, ad2);
    k_agg2<<<(NODES + 3) / 4, 256, 0, stream>>>(offs, csr, as2, ad2, hs2, b2, out);
}

// Round 12
// 182.577 us; speedup vs baseline: 1.0673x; 1.0673x over previous
//
#include <hip/hip_runtime.h>
#include <hip/hip_fp16.h>
#include <math.h>

#define NODES 100000
#define NEDGE 1600000
#define ETOT  (NEDGE + NODES)
#define FIN   128
#define C1    64
#define NEG   0.2f
#define BNEPS 1e-5f
#define BNBLK 256

#define BK     128                         // nodes per bucket
#define NBUCK  ((NODES + BK - 1) / BK)     // 782
#define PCAP   2816                        // per-bucket edge cap (mean 2048, +17 sigma)
#define PTILE  4096                        // edges per k_part block

typedef __attribute__((ext_vector_type(8))) short bf16x8;
typedef __attribute__((ext_vector_type(4))) float f32x4;

static __device__ __forceinline__ short f2bf(float f) {
    unsigned u = __builtin_bit_cast(unsigned, f);
    unsigned r = (u + 0x7FFFu + ((u >> 16) & 1u)) >> 16;
    return (short)r;
}

// ---------------- bucketed CSR build ----------------

__global__ __launch_bounds__(256) void k_zeroN(int* p, int n) {
    int i = blockIdx.x * 256 + threadIdx.x;
    if (i < n) p[i] = 0;
}

// P1: partition edges into buckets by dst>>7; pack src | (dst&127)<<17
__global__ __launch_bounds__(256) void k_part(const int* __restrict__ ei, int* bcur,
                                              unsigned* __restrict__ tmp) {
    __shared__ int hist[NBUCK], hbase[NBUCK], run[NBUCK];
    int t = threadIdx.x;
    for (int i = t; i < NBUCK; i += 256) { hist[i] = 0; run[i] = 0; }
    __syncthreads();
    const int* srcs = ei;
    const int* dsts = ei + NEDGE;
    int e_base = blockIdx.x * PTILE;
    unsigned pack[16];
    int bkt[16];
    #pragma unroll
    for (int i = 0; i < 16; i++) {
        int e = e_base + i * 256 + t;
        bool valid = e < NEDGE;
        int s = valid ? srcs[e] : 0;
        int d = valid ? dsts[e] : 0;
        if ((unsigned)d >= NODES || (unsigned)s >= NODES) valid = false;
        bkt[i] = valid ? (d >> 7) : -1;
        pack[i] = (unsigned)s | ((unsigned)(d & (BK - 1)) << 17);
        if (valid) atomicAdd(&hist[bkt[i]], 1);
    }
    __syncthreads();
    for (int i = t; i < NBUCK; i += 256)
        hbase[i] = hist[i] ? atomicAdd(&bcur[i], hist[i]) : 0;
    __syncthreads();
    #pragma unroll
    for (int i = 0; i < 16; i++) {
        if (bkt[i] >= 0) {
            int slot = atomicAdd(&run[bkt[i]], 1) + hbase[bkt[i]];
            if (slot < PCAP) tmp[(size_t)bkt[i] * PCAP + slot] = pack[i];
        }
    }
}

// exclusive scan of NBUCK bucket totals (single block, 4 items/thread)
__global__ __launch_bounds__(256) void k_bscan(const int* __restrict__ bcur, int* __restrict__ bbase) {
    __shared__ int lds[256];
    int t = threadIdx.x;
    int base = t * 4;
    int v0 = (base + 0) < NBUCK ? bcur[base + 0] : 0;
    int v1 = (base + 1) < NBUCK ? bcur[base + 1] : 0;
    int v2 = (base + 2) < NBUCK ? bcur[base + 2] : 0;
    int v3 = (base + 3) < NBUCK ? bcur[base + 3] : 0;
    int tot = v0 + v1 + v2 + v3;
    lds[t] = tot;
    __syncthreads();
    for (int o = 1; o < 256; o <<= 1) {
        int add = (t >= o) ? lds[t - o] : 0;
        __syncthreads();
        lds[t] += add;
        __syncthreads();
    }
    int excl = lds[t] - tot;
    if (base + 0 < NBUCK) bbase[base + 0] = excl;
    if (base + 1 < NBUCK) bbase[base + 1] = excl + v0;
    if (base + 2 < NBUCK) bbase[base + 2] = excl + v0 + v1;
    if (base + 3 < NBUCK) bbase[base + 3] = excl + v0 + v1 + v2;
}

// P2: per bucket: counts -> local scan (offs) -> LDS scatter -> coalesced csr+pe write.
// p = exp(lrelu(as1[s]+ad1[d])) computed inline at writeout (as1/ad1 ready: gemm1 runs first).
__global__ __launch_bounds__(256) void k_build(const unsigned* __restrict__ tmp, const int* __restrict__ bcur,
                                               const int* __restrict__ bbase,
                                               const float* __restrict__ as1, const float* __restrict__ ad1,
                                               int* __restrict__ offs, int* __restrict__ csr,
                                               uint2* __restrict__ pe) {
    __shared__ int cnt[BK];
    __shared__ int ps_[BK];
    __shared__ int stage[PCAP + BK];
    int t = threadIdx.x;
    int b = blockIdx.x;
    int ecnt = bcur[b]; if (ecnt > PCAP) ecnt = PCAP;
    int csrbase = bbase[b] + BK * b;   // earlier buckets all have BK self-loops
    const unsigned* ebuf = tmp + (size_t)b * PCAP;

    if (t < BK) cnt[t] = 0;
    __syncthreads();
    for (int e = t; e < ecnt; e += 256) {
        int dl = (ebuf[e] >> 17) & (BK - 1);
        atomicAdd(&cnt[dl], 1);
    }
    __syncthreads();
    int gn = b * BK + t;
    int own = 0;
    if (t < BK) {
        own = cnt[t] + ((gn < NODES) ? 1 : 0);   // +1 self-loop
        ps_[t] = own;
    }
    __syncthreads();
    for (int o = 1; o < BK; o <<= 1) {
        int add = (t < BK && t >= o) ? ps_[t - o] : 0;
        __syncthreads();
        if (t < BK) ps_[t] += add;
        __syncthreads();
    }
    int total = ps_[BK - 1];
    if (t < BK && gn < NODES) {
        int excl = ps_[t] - own;
        stage[excl] = gn | (t << 17);     // self-loop, packed (src=gn, dl=t)
        cnt[t] = excl + 1;
        offs[gn] = csrbase + excl;
    }
    if (b == NBUCK - 1 && t == 0) offs[NODES] = ETOT;
    if (b == NBUCK - 1 && t < 16) pe[ETOT + t] = make_uint2(0u, 0u);   // tail pad
    __syncthreads();
    for (int e = t; e < ecnt; e += 256) {
        unsigned p = ebuf[e];
        int dl = (p >> 17) & (BK - 1);
        int slot = atomicAdd(&cnt[dl], 1);
        stage[slot] = (int)p;
    }
    __syncthreads();
    for (int j = t; j < total; j += 256) {
        int v = stage[j];
        int s = v & 0x1FFFF;
        int d = b * BK + (int)(((unsigned)v) >> 17);
        csr[csrbase + j] = s;
        float e = as1[s] + ad1[d];
        e = e > 0.f ? e : NEG * e;
        float p = __expf(fminf(e, 60.f));
        pe[csrbase + j] = make_uint2((unsigned)s, __float_as_uint(p));
    }
}

// ---------------- prep: wad vectors + W1s bf16 B-fragments ----------------

__global__ __launch_bounds__(256) void k_prep(const float* __restrict__ W1s,
                                              const float* __restrict__ W1d, const float* __restrict__ a1d,
                                              const float* __restrict__ W2d, const float* __restrict__ a2d,
                                              float* wad1, float* wad2, unsigned short* __restrict__ wfrag) {
    int t = threadIdx.x;
    int b = blockIdx.x;
    if (b == 32) {
        if (t < FIN) {
            float acc = 0.f;
            for (int c = 0; c < C1; c++) acc = fmaf(W1d[t * C1 + c], a1d[c], acc);
            wad1[t] = acc;
        }
        if (t < C1) {
            wad2[t] = fmaf(W2d[t * 2], a2d[0], W2d[t * 2 + 1] * a2d[1]);
        }
    } else {
        int idx = b * 256 + t;          // 0..8191
        int j  = idx & 7;
        int ln = (idx >> 3) & 63;
        int it = (idx >> 9) & 3;
        int ct = idx >> 11;
        int k  = it * 32 + (ln >> 4) * 8 + j;
        int ch = ct * 16 + (ln & 15);
        wfrag[idx] = (unsigned short)f2bf(W1s[k * C1 + ch]);
    }
}

// ---------------- GEMM1 via MFMA ----------------

__global__ __launch_bounds__(256) void k_gemm1(const float* __restrict__ x,
                                               const unsigned short* __restrict__ wfrag,
                                               const float* __restrict__ wad, const float* __restrict__ a_src,
                                               __half* __restrict__ hsh, float* __restrict__ as_out,
                                               float* __restrict__ ad_out) {
    int t = threadIdx.x;
    int lane = t & 63;
    int wv = t >> 6;
    int n0 = blockIdx.x * 64 + wv * 16;
    int li = lane & 15, g = lane >> 4;

    int row = n0 + li;
    bool rv = row < NODES;
    const float* xr = x + (size_t)row * FIN + g * 8;

    f32x4 acc0 = {0.f,0.f,0.f,0.f}, acc1 = {0.f,0.f,0.f,0.f};
    f32x4 acc2 = {0.f,0.f,0.f,0.f}, acc3 = {0.f,0.f,0.f,0.f};
    bf16x8 af[4];
    float adp = 0.f;

    #pragma unroll
    for (int it = 0; it < 4; it++) {
        float xv[8];
        if (rv) {
            float4 lo = *reinterpret_cast<const float4*>(xr + it * 32);
            float4 hi = *reinterpret_cast<const float4*>(xr + it * 32 + 4);
            xv[0]=lo.x; xv[1]=lo.y; xv[2]=lo.z; xv[3]=lo.w;
            xv[4]=hi.x; xv[5]=hi.y; xv[6]=hi.z; xv[7]=hi.w;
        } else {
            #pragma unroll
            for (int j = 0; j < 8; j++) xv[j] = 0.f;
        }
        const float* wr = wad + g * 8 + it * 32;
        float4 wlo = *reinterpret_cast<const float4*>(wr);
        float4 whi = *reinterpret_cast<const float4*>(wr + 4);
        adp = fmaf(xv[0], wlo.x, adp); adp = fmaf(xv[1], wlo.y, adp);
        adp = fmaf(xv[2], wlo.z, adp); adp = fmaf(xv[3], wlo.w, adp);
        adp = fmaf(xv[4], whi.x, adp); adp = fmaf(xv[5], whi.y, adp);
        adp = fmaf(xv[6], whi.z, adp); adp = fmaf(xv[7], whi.w, adp);
        bf16x8 a;
        #pragma unroll
        for (int j = 0; j < 8; j++) a[j] = f2bf(xv[j]);
        af[it] = a;
    }

    const bf16x8* wfv = reinterpret_cast<const bf16x8*>(wfrag);
    #pragma unroll
    for (int it = 0; it < 4; it++) {
        acc0 = __builtin_amdgcn_mfma_f32_16x16x32_bf16(af[it], wfv[(0*4+it)*64 + lane], acc0, 0, 0, 0);
        acc1 = __builtin_amdgcn_mfma_f32_16x16x32_bf16(af[it], wfv[(1*4+it)*64 + lane], acc1, 0, 0, 0);
        acc2 = __builtin_amdgcn_mfma_f32_16x16x32_bf16(af[it], wfv[(2*4+it)*64 + lane], acc2, 0, 0, 0);
        acc3 = __builtin_amdgcn_mfma_f32_16x16x32_bf16(af[it], wfv[(3*4+it)*64 + lane], acc3, 0, 0, 0);
    }

    adp += __shfl_xor(adp, 16);
    adp += __shfl_xor(adp, 32);
    if (lane < 16 && rv) ad_out[row] = adp;

    float a0 = a_src[0 * 16 + li], a1 = a_src[1 * 16 + li];
    float a2 = a_src[2 * 16 + li], a3 = a_src[3 * 16 + li];
    float asp0 = acc0[0]*a0 + acc1[0]*a1 + acc2[0]*a2 + acc3[0]*a3;
    float asp1 = acc0[1]*a0 + acc1[1]*a1 + acc2[1]*a2 + acc3[1]*a3;
    float asp2 = acc0[2]*a0 + acc1[2]*a1 + acc2[2]*a2 + acc3[2]*a3;
    float asp3 = acc0[3]*a0 + acc1[3]*a1 + acc2[3]*a2 + acc3[3]*a3;
    #pragma unroll
    for (int o = 1; o <= 8; o <<= 1) {
        asp0 += __shfl_xor(asp0, o);
        asp1 += __shfl_xor(asp1, o);
        asp2 += __shfl_xor(asp2, o);
        asp3 += __shfl_xor(asp3, o);
    }
    if ((lane & 12) == 0) {
        int r = lane & 3;
        int n = n0 + 4 * g + r;
        if (n < NODES) {
            float av = (r == 0) ? asp0 : (r == 1) ? asp1 : (r == 2) ? asp2 : asp3;
            as_out[n] = av;
        }
    }

    #pragma unroll
    for (int r = 0; r < 4; r++) {
        int n = n0 + 4 * g + r;
        if (n < NODES) {
            __half* hb = hsh + (size_t)n * C1 + li;
            hb[ 0] = __float2half(acc0[r]);
            hb[16] = __float2half(acc1[r]);
            hb[32] = __float2half(acc2[r]);
            hb[48] = __float2half(acc3[r]);
        }
    }
}

// ---------------- aggregation layer 1: pure gather, 16 edges in flight ----------------
// wave per node; 4 groups x 16 lanes; per iteration 4 independent broadcast pe loads +
// 4 independent row-gather instructions (each covering 4 rows of 128B). Invalid slots
// clamp to row 0 (L1-hot) with p=0.

__global__ __launch_bounds__(256) void k_agg1(const int* __restrict__ offs, const uint2* __restrict__ pe,
                                              const __half* __restrict__ hsh, const float* __restrict__ b1,
                                              float* __restrict__ h1) {
    int w = threadIdx.x >> 6, lane = threadIdx.x & 63;
    int node = blockIdx.x * 4 + w;
    if (node >= NODES) return;
    int e0 = offs[node], e1 = offs[node + 1];
    int g = lane >> 4, l = lane & 15;
    float acc0 = 0.f, acc1 = 0.f, acc2 = 0.f, acc3 = 0.f, ssum = 0.f;
    for (int base = e0; base < e1; base += 16) {
        int ea = base + g, eb = ea + 4, ec = ea + 8, ed = ea + 12;
        uint2 spa = pe[ea];
        uint2 spb = pe[eb];
        uint2 spc = pe[ec];
        uint2 spd = pe[ed];
        bool va = ea < e1, vb = eb < e1, vc = ec < e1, vd = ed < e1;
        int   sa = va ? (int)spa.x : 0;
        int   sb = vb ? (int)spb.x : 0;
        int   sc = vc ? (int)spc.x : 0;
        int   sd = vd ? (int)spd.x : 0;
        float pa = va ? __uint_as_float(spa.y) : 0.f;
        float pb = vb ? __uint_as_float(spb.y) : 0.f;
        float pc = vc ? __uint_as_float(spc.y) : 0.f;
        float pd = vd ? __uint_as_float(spd.y) : 0.f;
        uint2 ra = *reinterpret_cast<const uint2*>(hsh + (size_t)sa * C1 + l * 4);
        uint2 rb = *reinterpret_cast<const uint2*>(hsh + (size_t)sb * C1 + l * 4);
        uint2 rc = *reinterpret_cast<const uint2*>(hsh + (size_t)sc * C1 + l * 4);
        uint2 rd = *reinterpret_cast<const uint2*>(hsh + (size_t)sd * C1 + l * 4);
        ssum += (pa + pb) + (pc + pd);
        float2 a01 = __half22float2(*reinterpret_cast<const __half2*>(&ra.x));
        float2 a23 = __half22float2(*reinterpret_cast<const __half2*>(&ra.y));
        float2 b01 = __half22float2(*reinterpret_cast<const __half2*>(&rb.x));
        float2 b23 = __half22float2(*reinterpret_cast<const __half2*>(&rb.y));
        float2 c01 = __half22float2(*reinterpret_cast<const __half2*>(&rc.x));
        float2 c23 = __half22float2(*reinterpret_cast<const __half2*>(&rc.y));
        float2 d01 = __half22float2(*reinterpret_cast<const __half2*>(&rd.x));
        float2 d23 = __half22float2(*reinterpret_cast<const __half2*>(&rd.y));
        acc0 = fmaf(pa, a01.x, acc0); acc1 = fmaf(pa, a01.y, acc1);
        acc2 = fmaf(pa, a23.x, acc2); acc3 = fmaf(pa, a23.y, acc3);
        acc0 = fmaf(pb, b01.x, acc0); acc1 = fmaf(pb, b01.y, acc1);
        acc2 = fmaf(pb, b23.x, acc2); acc3 = fmaf(pb, b23.y, acc3);
        acc0 = fmaf(pc, c01.x, acc0); acc1 = fmaf(pc, c01.y, acc1);
        acc2 = fmaf(pc, c23.x, acc2); acc3 = fmaf(pc, c23.y, acc3);
        acc0 = fmaf(pd, d01.x, acc0); acc1 = fmaf(pd, d01.y, acc1);
        acc2 = fmaf(pd, d23.x, acc2); acc3 = fmaf(pd, d23.y, acc3);
    }
    ssum += __shfl_xor(ssum, 16); ssum += __shfl_xor(ssum, 32);
    acc0 += __shfl_xor(acc0, 16); acc0 += __shfl_xor(acc0, 32);
    acc1 += __shfl_xor(acc1, 16); acc1 += __shfl_xor(acc1, 32);
    acc2 += __shfl_xor(acc2, 16); acc2 += __shfl_xor(acc2, 32);
    acc3 += __shfl_xor(acc3, 16); acc3 += __shfl_xor(acc3, 32);
    if (g == 0) {
        float inv = 1.0f / (ssum + 1e-16f);
        float4 bv = reinterpret_cast<const float4*>(b1)[l];
        float4 r = make_float4(fmaf(acc0, inv, bv.x), fmaf(acc1, inv, bv.y),
                               fmaf(acc2, inv, bv.z), fmaf(acc3, inv, bv.w));
        reinterpret_cast<float4*>(h1 + (size_t)node * C1)[l] = r;
    }
}

// ---------------- BN stats: deterministic per-block partials ----------------

__global__ __launch_bounds__(256) void k_bnstats(const float* __restrict__ h1, float* __restrict__ bnpart) {
    __shared__ float ls[256], lq[256];
    int t = threadIdx.x;
    int c = t & 63, g = t >> 6;
    float s = 0.f, q = 0.f;
    for (int n = blockIdx.x * 4 + g; n < NODES; n += BNBLK * 4) {
        float v = h1[(size_t)n * C1 + c];
        s += v;
        q = fmaf(v, v, q);
    }
    ls[t] = s; lq[t] = q;
    __syncthreads();
    if (t < 64) {
        bnpart[(size_t)blockIdx.x * 128 + t]      = ls[t] + ls[t + 64] + ls[t + 128] + ls[t + 192];
        bnpart[(size_t)blockIdx.x * 128 + 64 + t] = lq[t] + lq[t + 64] + lq[t + 128] + lq[t + 192];
    }
}

__global__ __launch_bounds__(64) void k_bnfinal(const float* __restrict__ bnpart,
                                                const float* __restrict__ gamma, const float* __restrict__ beta,
                                                float* bnscale, float* bnshift) {
    int c = threadIdx.x;
    if (c < C1) {
        float s = 0.f, q = 0.f;
        for (int b = 0; b < BNBLK; b++) {
            s += bnpart[(size_t)b * 128 + c];
            q += bnpart[(size_t)b * 128 + 64 + c];
        }
        float mu = s * (1.0f / NODES);
        float var = q * (1.0f / NODES) - mu * mu;
        if (var < 0.f) var = 0.f;
        float rinv = 1.0f / sqrtf(var + BNEPS);
        float sc = gamma[c] * rinv;
        bnscale[c] = sc;
        bnshift[c] = beta[c] - mu * sc;
    }
}

// ---------------- BN apply + ReLU + GEMM2 (+alpha dots) ----------------

__global__ __launch_bounds__(256) void k_bngemm2(const float* __restrict__ h1, const float* __restrict__ bnscale,
                                                 const float* __restrict__ bnshift, const float* __restrict__ W2s,
                                                 const float* __restrict__ wad2, const float* __restrict__ a2s,
                                                 float* __restrict__ hs2, float* __restrict__ as2,
                                                 float* __restrict__ ad2) {
    int n = blockIdx.x * 256 + threadIdx.x;
    if (n >= NODES) return;
    const float4* hr = reinterpret_cast<const float4*>(h1 + (size_t)n * C1);
    float h0 = 0.f, h1v = 0.f, adv = 0.f;
    #pragma unroll
    for (int c4 = 0; c4 < 16; c4++) {
        float4 v = hr[c4];
        float vv[4] = {v.x, v.y, v.z, v.w};
        #pragma unroll
        for (int j = 0; j < 4; j++) {
            int c = c4 * 4 + j;
            float y = fmaf(vv[j], bnscale[c], bnshift[c]);
            y = fmaxf(y, 0.f);
            h0 = fmaf(y, W2s[c * 2 + 0], h0);
            h1v = fmaf(y, W2s[c * 2 + 1], h1v);
            adv = fmaf(y, wad2[c], adv);
        }
    }
    hs2[n * 2 + 0] = h0;
    hs2[n * 2 + 1] = h1v;
    as2[n] = fmaf(h0, a2s[0], h1v * a2s[1]);
    ad2[n] = adv;
}

// ---------------- aggregation layer 2: wave per node, fully lane-parallel ----------------

__global__ __launch_bounds__(256) void k_agg2(const int* __restrict__ offs, const int* __restrict__ csr,
                                              const float* __restrict__ as2, const float* __restrict__ ad2,
                                              const float* __restrict__ hs2, const float* __restrict__ b2,
                                              float* __restrict__ out) {
    int w = threadIdx.x >> 6, lane = threadIdx.x & 63;
    int node = blockIdx.x * 4 + w;
    if (node >= NODES) return;
    int e0 = offs[node], e1 = offs[node + 1];
    float adn = ad2[node];
    float ssum = 0.f, A0 = 0.f, A1 = 0.f;
    const float2* h2 = reinterpret_cast<const float2*>(hs2);
    for (int base = e0; base < e1; base += 64) {
        int e = base + lane;
        bool valid = e < e1;
        int s = valid ? csr[e] : 0;
        float v = valid ? (as2[s] + adn) : -INFINITY;
        v = v > 0.f ? v : NEG * v;
        float p = __expf(fminf(v, 60.f));
        ssum += p;
        float2 hv = valid ? h2[s] : make_float2(0.f, 0.f);
        A0 = fmaf(p, hv.x, A0);
        A1 = fmaf(p, hv.y, A1);
    }
    #pragma unroll
    for (int o = 32; o; o >>= 1) {
        ssum += __shfl_xor(ssum, o);
        A0   += __shfl_xor(A0, o);
        A1   += __shfl_xor(A1, o);
    }
    if (lane == 0) {
        float inv = 1.0f / (ssum + 1e-16f);
        float2 r = make_float2(fmaf(A0, inv, b2[0]), fmaf(A1, inv, b2[1]));
        reinterpret_cast<float2*>(out)[node] = r;
    }
}

// ---------------- host ----------------

static inline size_t align256(size_t x) { return (x + 255) & ~size_t(255); }

extern "C" void kernel_launch(void* const* d_in, const int* in_sizes, int n_in,
                              void* d_out, int out_size, void* d_ws, size_t ws_size,
                              hipStream_t stream) {
    const float* x     = (const float*)d_in[0];
    const int*   ei    = (const int*)d_in[1];
    const float* W1s   = (const float*)d_in[2];
    const float* W1d   = (const float*)d_in[3];
    const float* a1s   = (const float*)d_in[4];
    const float* a1d   = (const float*)d_in[5];
    const float* b1    = (const float*)d_in[6];
    const float* gamma = (const float*)d_in[7];
    const float* beta  = (const float*)d_in[8];
    const float* W2s   = (const float*)d_in[9];
    const float* W2d   = (const float*)d_in[10];
    const float* a2s   = (const float*)d_in[11];
    const float* a2d   = (const float*)d_in[12];
    const float* b2    = (const float*)d_in[13];
    float* out = (float*)d_out;

    char* w = (char*)d_ws;
    size_t off = 0;
    auto alloc = [&](size_t bytes) -> void* {
        void* p = w + off;
        off = align256(off + bytes);
        return p;
    };
    int* offs     = (int*)alloc((size_t)(NODES + 1) * 4);
    int* bcur     = (int*)alloc((size_t)NBUCK * 4);
    int* bbase    = (int*)alloc((size_t)NBUCK * 4);
    int* csr      = (int*)alloc((size_t)ETOT * 4);
    uint2* pe     = (uint2*)alloc((size_t)(ETOT + 16) * 8);
    __half* hs1h  = (__half*)alloc((size_t)NODES * C1 * 2);   // fp16 gather payload
    float* as1    = (float*)alloc((size_t)NODES * 4);
    float* ad1    = (float*)alloc((size_t)NODES * 4);
    float* h1     = (float*)alloc((size_t)NODES * C1 * 4);   // aliases csr_tmp (below)
    float* hs2    = (float*)alloc((size_t)NODES * 2 * 4);
    float* as2    = (float*)alloc((size_t)NODES * 4);
    float* ad2    = (float*)alloc((size_t)NODES * 4);
    float* wad1   = (float*)alloc(FIN * 4);
    float* wad2   = (float*)alloc(C1 * 4);
    unsigned short* wfrag = (unsigned short*)alloc(8192 * 2); // W1s bf16 B-fragments
    float* bnpart = (float*)alloc((size_t)BNBLK * 128 * 4);
    float* bnsc   = (float*)alloc(64 * 4);
    float* bnsh   = (float*)alloc(64 * 4);
    if (off > ws_size) return;

    // csr_tmp (NBUCK*PCAP ints = 8.8MB) aliases h1 (25.6MB): k_build fully consumes
    // csr_tmp before k_agg1 produces h1 (in-order stream => safe).
    unsigned* csr_tmp = (unsigned*)h1;

    k_zeroN<<<(NBUCK + 255) / 256, 256, 0, stream>>>(bcur, NBUCK);
    k_part<<<(NEDGE + PTILE - 1) / PTILE, 256, 0, stream>>>(ei, bcur, csr_tmp);
    k_bscan<<<1, 256, 0, stream>>>(bcur, bbase);
    k_prep<<<33, 256, 0, stream>>>(W1s, W1d, a1d, W2d, a2d, wad1, wad2, wfrag);
    k_gemm1<<<(NODES + 63) / 64, 256, 0, stream>>>(x, wfrag, wad1, a1s, hs1h, as1, ad1);
    k_build<<<NBUCK, 256, 0, stream>>>(csr_tmp, bcur, bbase, as1, ad1, offs, csr, pe);
    k_agg1<<<(NODES + 3) / 4, 256, 0, stream>>>(offs, pe, hs1h, b1, h1);
    k_bnstats<<<BNBLK, 256, 0, stream>>>(h1, bnpart);
    k_bnfinal<<<1, 64, 0, stream>>>(bnpart, gamma, beta, bnsc, bnsh);
    k_bngemm2<<<(NODES + 255) / 256, 256, 0, stream>>>(h1, bnsc, bnsh, W2s, wad2, a2s, hs2, as2, ad2);
    k_agg2<<<(NODES + 3) / 4, 256, 0, stream>>>(offs, csr, as2, ad2, hs2, b2, out);
}

// Round 13
// 180.383 us; speedup vs baseline: 1.0803x; 1.0122x over previous
//
#include <hip/hip_runtime.h>
#include <hip/hip_fp16.h>
#include <math.h>

#define NODES 100000
#define NEDGE 1600000
#define ETOT  (NEDGE + NODES)
#define FIN   128
#define C1    64
#define NEG   0.2f
#define BNEPS 1e-5f
#define BNBLK 256
#define PSCALE 0.00390625f   // 2^-8 : fp16 accumulation scale in agg1

#define BK     128                         // nodes per bucket
#define NBUCK  ((NODES + BK - 1) / BK)     // 782
#define PCAP   2816                        // per-bucket edge cap (mean 2048, +17 sigma)
#define PTILE  4096                        // edges per k_part block

typedef __attribute__((ext_vector_type(8))) short bf16x8;
typedef __attribute__((ext_vector_type(4))) float f32x4;

static __device__ __forceinline__ short f2bf(float f) {
    unsigned u = __builtin_bit_cast(unsigned, f);
    unsigned r = (u + 0x7FFFu + ((u >> 16) & 1u)) >> 16;
    return (short)r;
}

// ---------------- prep: wad vectors + W1s bf16 B-fragments + bcur zero ----------------

__global__ __launch_bounds__(256) void k_prep(const float* __restrict__ W1s,
                                              const float* __restrict__ W1d, const float* __restrict__ a1d,
                                              const float* __restrict__ W2d, const float* __restrict__ a2d,
                                              float* wad1, float* wad2, unsigned short* __restrict__ wfrag,
                                              int* __restrict__ bcur) {
    int t = threadIdx.x;
    int b = blockIdx.x;
    if (b == 33) {
        for (int i = t; i < NBUCK; i += 256) bcur[i] = 0;
    } else if (b == 32) {
        if (t < FIN) {
            float acc = 0.f;
            for (int c = 0; c < C1; c++) acc = fmaf(W1d[t * C1 + c], a1d[c], acc);
            wad1[t] = acc;
        }
        if (t < C1) {
            wad2[t] = fmaf(W2d[t * 2], a2d[0], W2d[t * 2 + 1] * a2d[1]);
        }
    } else {
        int idx = b * 256 + t;          // 0..8191
        int j  = idx & 7;
        int ln = (idx >> 3) & 63;
        int it = (idx >> 9) & 3;
        int ct = idx >> 11;
        int k  = it * 32 + (ln >> 4) * 8 + j;
        int ch = ct * 16 + (ln & 15);
        wfrag[idx] = (unsigned short)f2bf(W1s[k * C1 + ch]);
    }
}

// ---------------- bucketed CSR build ----------------

// P1: partition edges into buckets by dst>>7; single LDS-atomic pass.
__global__ __launch_bounds__(256) void k_part(const int* __restrict__ ei, int* bcur,
                                              unsigned* __restrict__ tmp) {
    __shared__ int hist[NBUCK], hbase[NBUCK];
    int t = threadIdx.x;
    for (int i = t; i < NBUCK; i += 256) hist[i] = 0;
    __syncthreads();
    const int* srcs = ei;
    const int* dsts = ei + NEDGE;
    int e_base = blockIdx.x * PTILE;
    unsigned pack[16];
    int bkt[16], slot[16];
    #pragma unroll
    for (int i = 0; i < 16; i++) {
        int e = e_base + i * 256 + t;
        bool valid = e < NEDGE;
        int s = valid ? srcs[e] : 0;
        int d = valid ? dsts[e] : 0;
        if ((unsigned)d >= NODES || (unsigned)s >= NODES) valid = false;
        bkt[i] = valid ? (d >> 7) : -1;
        pack[i] = (unsigned)s | ((unsigned)(d & (BK - 1)) << 17);
        slot[i] = valid ? atomicAdd(&hist[bkt[i]], 1) : -1;
    }
    __syncthreads();
    for (int i = t; i < NBUCK; i += 256)
        hbase[i] = hist[i] ? atomicAdd(&bcur[i], hist[i]) : 0;
    __syncthreads();
    #pragma unroll
    for (int i = 0; i < 16; i++) {
        if (slot[i] >= 0) {
            int pos = hbase[bkt[i]] + slot[i];
            if (pos < PCAP) tmp[(size_t)bkt[i] * PCAP + pos] = pack[i];
        }
    }
}

// exclusive scan of NBUCK bucket totals (single block, 4 items/thread)
__global__ __launch_bounds__(256) void k_bscan(const int* __restrict__ bcur, int* __restrict__ bbase) {
    __shared__ int lds[256];
    int t = threadIdx.x;
    int base = t * 4;
    int v0 = (base + 0) < NBUCK ? bcur[base + 0] : 0;
    int v1 = (base + 1) < NBUCK ? bcur[base + 1] : 0;
    int v2 = (base + 2) < NBUCK ? bcur[base + 2] : 0;
    int v3 = (base + 3) < NBUCK ? bcur[base + 3] : 0;
    int tot = v0 + v1 + v2 + v3;
    lds[t] = tot;
    __syncthreads();
    for (int o = 1; o < 256; o <<= 1) {
        int add = (t >= o) ? lds[t - o] : 0;
        __syncthreads();
        lds[t] += add;
        __syncthreads();
    }
    int excl = lds[t] - tot;
    if (base + 0 < NBUCK) bbase[base + 0] = excl;
    if (base + 1 < NBUCK) bbase[base + 1] = excl + v0;
    if (base + 2 < NBUCK) bbase[base + 2] = excl + v0 + v1;
    if (base + 3 < NBUCK) bbase[base + 3] = excl + v0 + v1 + v2;
}

// P2: per bucket: counts -> local scan (offs) -> LDS scatter -> coalesced csr+pe write.
// p = exp(lrelu(as1[s]+ad1[d])) computed inline at writeout (gemm1 runs first).
__global__ __launch_bounds__(256) void k_build(const unsigned* __restrict__ tmp, const int* __restrict__ bcur,
                                               const int* __restrict__ bbase,
                                               const float* __restrict__ as1, const float* __restrict__ ad1,
                                               int* __restrict__ offs, int* __restrict__ csr,
                                               uint2* __restrict__ pe) {
    __shared__ int cnt[BK];
    __shared__ int ps_[BK];
    __shared__ int stage[PCAP + BK];
    int t = threadIdx.x;
    int b = blockIdx.x;
    int ecnt = bcur[b]; if (ecnt > PCAP) ecnt = PCAP;
    int csrbase = bbase[b] + BK * b;   // earlier buckets all have BK self-loops
    const unsigned* ebuf = tmp + (size_t)b * PCAP;

    if (t < BK) cnt[t] = 0;
    __syncthreads();
    for (int e = t; e < ecnt; e += 256) {
        int dl = (ebuf[e] >> 17) & (BK - 1);
        atomicAdd(&cnt[dl], 1);
    }
    __syncthreads();
    int gn = b * BK + t;
    int own = 0;
    if (t < BK) {
        own = cnt[t] + ((gn < NODES) ? 1 : 0);   // +1 self-loop
        ps_[t] = own;
    }
    __syncthreads();
    for (int o = 1; o < BK; o <<= 1) {
        int add = (t < BK && t >= o) ? ps_[t - o] : 0;
        __syncthreads();
        if (t < BK) ps_[t] += add;
        __syncthreads();
    }
    int total = ps_[BK - 1];
    if (t < BK && gn < NODES) {
        int excl = ps_[t] - own;
        stage[excl] = gn | (t << 17);     // self-loop, packed (src=gn, dl=t)
        cnt[t] = excl + 1;
        offs[gn] = csrbase + excl;
    }
    if (b == NBUCK - 1 && t == 0) offs[NODES] = ETOT;
    if (b == NBUCK - 1 && t < 16) pe[ETOT + t] = make_uint2(0u, 0u);   // tail pad
    __syncthreads();
    for (int e = t; e < ecnt; e += 256) {
        unsigned p = ebuf[e];
        int dl = (p >> 17) & (BK - 1);
        int slot = atomicAdd(&cnt[dl], 1);
        stage[slot] = (int)p;
    }
    __syncthreads();
    for (int j = t; j < total; j += 256) {
        int v = stage[j];
        int s = v & 0x1FFFF;
        int d = b * BK + (int)(((unsigned)v) >> 17);
        csr[csrbase + j] = s;
        float e = as1[s] + ad1[d];
        e = e > 0.f ? e : NEG * e;
        float p = __expf(fminf(e, 60.f));
        pe[csrbase + j] = make_uint2((unsigned)s, __float_as_uint(p));
    }
}

// ---------------- GEMM1 via MFMA ----------------

__global__ __launch_bounds__(256) void k_gemm1(const float* __restrict__ x,
                                               const unsigned short* __restrict__ wfrag,
                                               const float* __restrict__ wad, const float* __restrict__ a_src,
                                               __half* __restrict__ hsh, float* __restrict__ as_out,
                                               float* __restrict__ ad_out) {
    int t = threadIdx.x;
    int lane = t & 63;
    int wv = t >> 6;
    int n0 = blockIdx.x * 64 + wv * 16;
    int li = lane & 15, g = lane >> 4;

    int row = n0 + li;
    bool rv = row < NODES;
    const float* xr = x + (size_t)row * FIN + g * 8;

    f32x4 acc0 = {0.f,0.f,0.f,0.f}, acc1 = {0.f,0.f,0.f,0.f};
    f32x4 acc2 = {0.f,0.f,0.f,0.f}, acc3 = {0.f,0.f,0.f,0.f};
    bf16x8 af[4];
    float adp = 0.f;

    #pragma unroll
    for (int it = 0; it < 4; it++) {
        float xv[8];
        if (rv) {
            float4 lo = *reinterpret_cast<const float4*>(xr + it * 32);
            float4 hi = *reinterpret_cast<const float4*>(xr + it * 32 + 4);
            xv[0]=lo.x; xv[1]=lo.y; xv[2]=lo.z; xv[3]=lo.w;
            xv[4]=hi.x; xv[5]=hi.y; xv[6]=hi.z; xv[7]=hi.w;
        } else {
            #pragma unroll
            for (int j = 0; j < 8; j++) xv[j] = 0.f;
        }
        const float* wr = wad + g * 8 + it * 32;
        float4 wlo = *reinterpret_cast<const float4*>(wr);
        float4 whi = *reinterpret_cast<const float4*>(wr + 4);
        adp = fmaf(xv[0], wlo.x, adp); adp = fmaf(xv[1], wlo.y, adp);
        adp = fmaf(xv[2], wlo.z, adp); adp = fmaf(xv[3], wlo.w, adp);
        adp = fmaf(xv[4], whi.x, adp); adp = fmaf(xv[5], whi.y, adp);
        adp = fmaf(xv[6], whi.z, adp); adp = fmaf(xv[7], whi.w, adp);
        bf16x8 a;
        #pragma unroll
        for (int j = 0; j < 8; j++) a[j] = f2bf(xv[j]);
        af[it] = a;
    }

    const bf16x8* wfv = reinterpret_cast<const bf16x8*>(wfrag);
    #pragma unroll
    for (int it = 0; it < 4; it++) {
        acc0 = __builtin_amdgcn_mfma_f32_16x16x32_bf16(af[it], wfv[(0*4+it)*64 + lane], acc0, 0, 0, 0);
        acc1 = __builtin_amdgcn_mfma_f32_16x16x32_bf16(af[it], wfv[(1*4+it)*64 + lane], acc1, 0, 0, 0);
        acc2 = __builtin_amdgcn_mfma_f32_16x16x32_bf16(af[it], wfv[(2*4+it)*64 + lane], acc2, 0, 0, 0);
        acc3 = __builtin_amdgcn_mfma_f32_16x16x32_bf16(af[it], wfv[(3*4+it)*64 + lane], acc3, 0, 0, 0);
    }

    adp += __shfl_xor(adp, 16);
    adp += __shfl_xor(adp, 32);
    if (lane < 16 && rv) ad_out[row] = adp;

    float a0 = a_src[0 * 16 + li], a1 = a_src[1 * 16 + li];
    float a2 = a_src[2 * 16 + li], a3 = a_src[3 * 16 + li];
    float asp0 = acc0[0]*a0 + acc1[0]*a1 + acc2[0]*a2 + acc3[0]*a3;
    float asp1 = acc0[1]*a0 + acc1[1]*a1 + acc2[1]*a2 + acc3[1]*a3;
    float asp2 = acc0[2]*a0 + acc1[2]*a1 + acc2[2]*a2 + acc3[2]*a3;
    float asp3 = acc0[3]*a0 + acc1[3]*a1 + acc2[3]*a2 + acc3[3]*a3;
    #pragma unroll
    for (int o = 1; o <= 8; o <<= 1) {
        asp0 += __shfl_xor(asp0, o);
        asp1 += __shfl_xor(asp1, o);
        asp2 += __shfl_xor(asp2, o);
        asp3 += __shfl_xor(asp3, o);
    }
    if ((lane & 12) == 0) {
        int r = lane & 3;
        int n = n0 + 4 * g + r;
        if (n < NODES) {
            float av = (r == 0) ? asp0 : (r == 1) ? asp1 : (r == 2) ? asp2 : asp3;
            as_out[n] = av;
        }
    }

    #pragma unroll
    for (int r = 0; r < 4; r++) {
        int n = n0 + 4 * g + r;
        if (n < NODES) {
            __half* hb = hsh + (size_t)n * C1 + li;
            hb[ 0] = __float2half(acc0[r]);
            hb[16] = __float2half(acc1[r]);
            hb[32] = __float2half(acc2[r]);
            hb[48] = __float2half(acc3[r]);
        }
    }
}

// ---------------- aggregation layer 1: pure gather, packed-fp16 accumulate ----------------
// wave per node; 4 groups x 16 lanes; 16 edges in flight. acc in __half2 (p scaled by
// 2^-8: |e|<=~12 -> p*2^-8 <= ~640, terms well under fp16 range); ssum fp32;
// h1 = acc*256/ssum. Invalid slots: p masked to 0 (s unmasked -> row 0, harmless).

__global__ __launch_bounds__(256) void k_agg1(const int* __restrict__ offs, const uint2* __restrict__ pe,
                                              const __half* __restrict__ hsh, const float* __restrict__ b1,
                                              float* __restrict__ h1) {
    int w = threadIdx.x >> 6, lane = threadIdx.x & 63;
    int node = blockIdx.x * 4 + w;
    if (node >= NODES) return;
    int e0 = offs[node], e1 = offs[node + 1];
    int g = lane >> 4, l = lane & 15;
    __half2 acc01 = __floats2half2_rn(0.f, 0.f);
    __half2 acc23 = __floats2half2_rn(0.f, 0.f);
    float ssum = 0.f;
    for (int base = e0; base < e1; base += 16) {
        int ea = base + g, eb = ea + 4, ec = ea + 8, ed = ea + 12;
        uint2 spa = pe[ea];
        uint2 spb = pe[eb];
        uint2 spc = pe[ec];
        uint2 spd = pe[ed];
        float pa = ea < e1 ? __uint_as_float(spa.y) : 0.f;
        float pb = eb < e1 ? __uint_as_float(spb.y) : 0.f;
        float pc = ec < e1 ? __uint_as_float(spc.y) : 0.f;
        float pd = ed < e1 ? __uint_as_float(spd.y) : 0.f;
        uint2 ra = *reinterpret_cast<const uint2*>(hsh + (size_t)spa.x * C1 + l * 4);
        uint2 rb = *reinterpret_cast<const uint2*>(hsh + (size_t)spb.x * C1 + l * 4);
        uint2 rc = *reinterpret_cast<const uint2*>(hsh + (size_t)spc.x * C1 + l * 4);
        uint2 rd = *reinterpret_cast<const uint2*>(hsh + (size_t)spd.x * C1 + l * 4);
        ssum += (pa + pb) + (pc + pd);
        __half2 pha = __float2half2_rn(pa * PSCALE);
        __half2 phb = __float2half2_rn(pb * PSCALE);
        __half2 phc = __float2half2_rn(pc * PSCALE);
        __half2 phd = __float2half2_rn(pd * PSCALE);
        acc01 = __hfma2(pha, *reinterpret_cast<const __half2*>(&ra.x), acc01);
        acc23 = __hfma2(pha, *reinterpret_cast<const __half2*>(&ra.y), acc23);
        acc01 = __hfma2(phb, *reinterpret_cast<const __half2*>(&rb.x), acc01);
        acc23 = __hfma2(phb, *reinterpret_cast<const __half2*>(&rb.y), acc23);
        acc01 = __hfma2(phc, *reinterpret_cast<const __half2*>(&rc.x), acc01);
        acc23 = __hfma2(phc, *reinterpret_cast<const __half2*>(&rc.y), acc23);
        acc01 = __hfma2(phd, *reinterpret_cast<const __half2*>(&rd.x), acc01);
        acc23 = __hfma2(phd, *reinterpret_cast<const __half2*>(&rd.y), acc23);
    }
    ssum += __shfl_xor(ssum, 16); ssum += __shfl_xor(ssum, 32);
    // half2 cross-lane reduce via bitcast
    unsigned u01 = *reinterpret_cast<unsigned*>(&acc01);
    unsigned u23 = *reinterpret_cast<unsigned*>(&acc23);
    unsigned v01 = (unsigned)__shfl_xor((int)u01, 16);
    unsigned v23 = (unsigned)__shfl_xor((int)u23, 16);
    acc01 = __hadd2(acc01, *reinterpret_cast<__half2*>(&v01));
    acc23 = __hadd2(acc23, *reinterpret_cast<__half2*>(&v23));
    u01 = *reinterpret_cast<unsigned*>(&acc01);
    u23 = *reinterpret_cast<unsigned*>(&acc23);
    v01 = (unsigned)__shfl_xor((int)u01, 32);
    v23 = (unsigned)__shfl_xor((int)u23, 32);
    acc01 = __hadd2(acc01, *reinterpret_cast<__half2*>(&v01));
    acc23 = __hadd2(acc23, *reinterpret_cast<__half2*>(&v23));
    if (g == 0) {
        float inv = 256.0f / (ssum + 1e-16f);
        float2 f01 = __half22float2(acc01);
        float2 f23 = __half22float2(acc23);
        float4 bv = reinterpret_cast<const float4*>(b1)[l];
        float4 r = make_float4(fmaf(f01.x, inv, bv.x), fmaf(f01.y, inv, bv.y),
                               fmaf(f23.x, inv, bv.z), fmaf(f23.y, inv, bv.w));
        reinterpret_cast<float4*>(h1 + (size_t)node * C1)[l] = r;
    }
}

// ---------------- BN stats: deterministic per-block partials ----------------

__global__ __launch_bounds__(256) void k_bnstats(const float* __restrict__ h1, float* __restrict__ bnpart) {
    __shared__ float ls[256], lq[256];
    int t = threadIdx.x;
    int c = t & 63, g = t >> 6;
    float s = 0.f, q = 0.f;
    for (int n = blockIdx.x * 4 + g; n < NODES; n += BNBLK * 4) {
        float v = h1[(size_t)n * C1 + c];
        s += v;
        q = fmaf(v, v, q);
    }
    ls[t] = s; lq[t] = q;
    __syncthreads();
    if (t < 64) {
        bnpart[(size_t)blockIdx.x * 128 + t]      = ls[t] + ls[t + 64] + ls[t + 128] + ls[t + 192];
        bnpart[(size_t)blockIdx.x * 128 + 64 + t] = lq[t] + lq[t + 64] + lq[t + 128] + lq[t + 192];
    }
}

__global__ __launch_bounds__(64) void k_bnfinal(const float* __restrict__ bnpart,
                                                const float* __restrict__ gamma, const float* __restrict__ beta,
                                                float* bnscale, float* bnshift) {
    int c = threadIdx.x;
    if (c < C1) {
        float s = 0.f, q = 0.f;
        for (int b = 0; b < BNBLK; b++) {
            s += bnpart[(size_t)b * 128 + c];
            q += bnpart[(size_t)b * 128 + 64 + c];
        }
        float mu = s * (1.0f / NODES);
        float var = q * (1.0f / NODES) - mu * mu;
        if (var < 0.f) var = 0.f;
        float rinv = 1.0f / sqrtf(var + BNEPS);
        float sc = gamma[c] * rinv;
        bnscale[c] = sc;
        bnshift[c] = beta[c] - mu * sc;
    }
}

// ---------------- BN apply + ReLU + GEMM2 (+alpha dots) ----------------

__global__ __launch_bounds__(256) void k_bngemm2(const float* __restrict__ h1, const float* __restrict__ bnscale,
                                                 const float* __restrict__ bnshift, const float* __restrict__ W2s,
                                                 const float* __restrict__ wad2, const float* __restrict__ a2s,
                                                 float* __restrict__ hs2, float* __restrict__ as2,
                                                 float* __restrict__ ad2) {
    int n = blockIdx.x * 256 + threadIdx.x;
    if (n >= NODES) return;
    const float4* hr = reinterpret_cast<const float4*>(h1 + (size_t)n * C1);
    float h0 = 0.f, h1v = 0.f, adv = 0.f;
    #pragma unroll
    for (int c4 = 0; c4 < 16; c4++) {
        float4 v = hr[c4];
        float vv[4] = {v.x, v.y, v.z, v.w};
        #pragma unroll
        for (int j = 0; j < 4; j++) {
            int c = c4 * 4 + j;
            float y = fmaf(vv[j], bnscale[c], bnshift[c]);
            y = fmaxf(y, 0.f);
            h0 = fmaf(y, W2s[c * 2 + 0], h0);
            h1v = fmaf(y, W2s[c * 2 + 1], h1v);
            adv = fmaf(y, wad2[c], adv);
        }
    }
    hs2[n * 2 + 0] = h0;
    hs2[n * 2 + 1] = h1v;
    as2[n] = fmaf(h0, a2s[0], h1v * a2s[1]);
    ad2[n] = adv;
}

// ---------------- aggregation layer 2: wave per node, fully lane-parallel ----------------

__global__ __launch_bounds__(256) void k_agg2(const int* __restrict__ offs, const int* __restrict__ csr,
                                              const float* __restrict__ as2, const float* __restrict__ ad2,
                                              const float* __restrict__ hs2, const float* __restrict__ b2,
                                              float* __restrict__ out) {
    int w = threadIdx.x >> 6, lane = threadIdx.x & 63;
    int node = blockIdx.x * 4 + w;
    if (node >= NODES) return;
    int e0 = offs[node], e1 = offs[node + 1];
    float adn = ad2[node];
    float ssum = 0.f, A0 = 0.f, A1 = 0.f;
    const float2* h2 = reinterpret_cast<const float2*>(hs2);
    for (int base = e0; base < e1; base += 64) {
        int e = base + lane;
        bool valid = e < e1;
        int s = valid ? csr[e] : 0;
        float v = valid ? (as2[s] + adn) : -INFINITY;
        v = v > 0.f ? v : NEG * v;
        float p = __expf(fminf(v, 60.f));
        ssum += p;
        float2 hv = valid ? h2[s] : make_float2(0.f, 0.f);
        A0 = fmaf(p, hv.x, A0);
        A1 = fmaf(p, hv.y, A1);
    }
    #pragma unroll
    for (int o = 32; o; o >>= 1) {
        ssum += __shfl_xor(ssum, o);
        A0   += __shfl_xor(A0, o);
        A1   += __shfl_xor(A1, o);
    }
    if (lane == 0) {
        float inv = 1.0f / (ssum + 1e-16f);
        float2 r = make_float2(fmaf(A0, inv, b2[0]), fmaf(A1, inv, b2[1]));
        reinterpret_cast<float2*>(out)[node] = r;
    }
}

// ---------------- host ----------------

static inline size_t align256(size_t x) { return (x + 255) & ~size_t(255); }

extern "C" void kernel_launch(void* const* d_in, const int* in_sizes, int n_in,
                              void* d_out, int out_size, void* d_ws, size_t ws_size,
                              hipStream_t stream) {
    const float* x     = (const float*)d_in[0];
    const int*   ei    = (const int*)d_in[1];
    const float* W1s   = (const float*)d_in[2];
    const float* W1d   = (const float*)d_in[3];
    const float* a1s   = (const float*)d_in[4];
    const float* a1d   = (const float*)d_in[5];
    const float* b1    = (const float*)d_in[6];
    const float* gamma = (const float*)d_in[7];
    const float* beta  = (const float*)d_in[8];
    const float* W2s   = (const float*)d_in[9];
    const float* W2d   = (const float*)d_in[10];
    const float* a2s   = (const float*)d_in[11];
    const float* a2d   = (const float*)d_in[12];
    const float* b2    = (const float*)d_in[13];
    float* out = (float*)d_out;

    char* w = (char*)d_ws;
    size_t off = 0;
    auto alloc = [&](size_t bytes) -> void* {
        void* p = w + off;
        off = align256(off + bytes);
        return p;
    };
    int* offs     = (int*)alloc((size_t)(NODES + 1) * 4);
    int* bcur     = (int*)alloc((size_t)NBUCK * 4);
    int* bbase    = (int*)alloc((size_t)NBUCK * 4);
    int* csr      = (int*)alloc((size_t)ETOT * 4);
    uint2* pe     = (uint2*)alloc((size_t)(ETOT + 16) * 8);
    __half* hs1h  = (__half*)alloc((size_t)NODES * C1 * 2);   // fp16 gather payload
    float* as1    = (float*)alloc((size_t)NODES * 4);
    float* ad1    = (float*)alloc((size_t)NODES * 4);
    float* h1     = (float*)alloc((size_t)NODES * C1 * 4);   // aliases csr_tmp (below)
    float* hs2    = (float*)alloc((size_t)NODES * 2 * 4);
    float* as2    = (float*)alloc((size_t)NODES * 4);
    float* ad2    = (float*)alloc((size_t)NODES * 4);
    float* wad1   = (float*)alloc(FIN * 4);
    float* wad2   = (float*)alloc(C1 * 4);
    unsigned short* wfrag = (unsigned short*)alloc(8192 * 2); // W1s bf16 B-fragments
    float* bnpart = (float*)alloc((size_t)BNBLK * 128 * 4);
    float* bnsc   = (float*)alloc(64 * 4);
    float* bnsh   = (float*)alloc(64 * 4);
    if (off > ws_size) return;

    // csr_tmp (NBUCK*PCAP ints = 8.8MB) aliases h1 (25.6MB): k_build fully consumes
    // csr_tmp before k_agg1 produces h1 (in-order stream => safe).
    unsigned* csr_tmp = (unsigned*)h1;

    k_prep<<<34, 256, 0, stream>>>(W1s, W1d, a1d, W2d, a2d, wad1, wad2, wfrag, bcur);
    k_part<<<(NEDGE + PTILE - 1) / PTILE, 256, 0, stream>>>(ei, bcur, csr_tmp);
    k_bscan<<<1, 256, 0, stream>>>(bcur, bbase);
    k_gemm1<<<(NODES + 63) / 64, 256, 0, stream>>>(x, wfrag, wad1, a1s, hs1h, as1, ad1);
    k_build<<<NBUCK, 256, 0, stream>>>(csr_tmp, bcur, bbase, as1, ad1, offs, csr, pe);
    k_agg1<<<(NODES + 3) / 4, 256, 0, stream>>>(offs, pe, hs1h, b1, h1);
    k_bnstats<<<BNBLK, 256, 0, stream>>>(h1, bnpart);
    k_bnfinal<<<1, 64, 0, stream>>>(bnpart, gamma, beta, bnsc, bnsh);
    k_bngemm2<<<(NODES + 255) / 256, 256, 0, stream>>>(h1, bnsc, bnsh, W2s, wad2, a2s, hs2, as2, ad2);
    k_agg2<<<(NODES + 3) / 4, 256, 0, stream>>>(offs, csr, as2, ad2, hs2, b2, out);
}